// Round 6
// baseline (128.000 us; speedup 1.0000x reference)
//
#include <hip/hip_runtime.h>

// x: (16, 3, 512, 512) fp32 -> magnitude (b,h,w) ++ angle (b,h,w), fp32.
// Sobel (kornia normalized, cross-correlation, 'edge' padding = clamp):
//   gx = 0.125*(r0[w+1]-r0[w-1]) + 0.25*(r1[w+1]-r1[w-1]) + 0.125*(r2[w+1]-r2[w-1])
//   gy = 0.125*(r2[w-1]-r0[w-1]) + 0.25*(r2[w]-r0[w]) + 0.125*(r2[w+1]-r0[w+1])
// Thread = 4 px x 2 output rows; 36 independent loads/thread.
// This round: 8 waves/SIMD occupancy (launch_bounds(256,8), <=64 VGPR) with
// wave-uniform addressing forced to SGPRs via readfirstlane (saddr loads).

constexpr int Hc = 512;
constexpr int Wc = 512;
constexpr int Cc = 3;

__global__ __launch_bounds__(256, 8) void sobel_mag_angle_kernel(
    const float* __restrict__ x, float* __restrict__ out, int B) {
    int tid = blockIdx.x * 256 + threadIdx.x;
    int l  = tid & 127;                 // 128 threads span one row (4 px each)
    int w0 = l << 2;

    // Wave-uniform components -> SGPR (saves vector address math + VGPRs).
    int hh = __builtin_amdgcn_readfirstlane((tid >> 7) & 255);  // row-pair idx
    int b  = __builtin_amdgcn_readfirstlane(tid >> 15);
    int h0 = hh << 1;
    int rm = (h0 == 0) ? 0 : h0 - 1;              // clamped row above
    int rp = (h0 + 2 < Hc) ? h0 + 2 : Hc - 1;     // clamped row below pair

    // Lane-varying clamped halo columns ('edge' padding).
    int wl = (w0 == 0) ? 0 : w0 - 1;
    int wr = (w0 + 4 < Wc) ? w0 + 4 : Wc - 1;

    const float* xb = x + (size_t)b * (Cc * Hc * Wc);

    float bm[2][4], bgx[2][4], bgy[2][4];

#pragma unroll
    for (int c = 0; c < Cc; ++c) {
        const float* base = xb + c * (Hc * Wc);        // uniform
        const float* p0 = base + rm * Wc;              // uniform row bases
        const float* p1 = base + h0 * Wc;
        const float* p2 = base + (h0 + 1) * Wc;
        const float* p3 = base + rp * Wc;

        // cols 0..5 = image cols w0-1 .. w0+4 (clamped at edges)
        float col[4][6];
        {
            float4 v0 = *(const float4*)(p0 + w0);
            float4 v1 = *(const float4*)(p1 + w0);
            float4 v2 = *(const float4*)(p2 + w0);
            float4 v3 = *(const float4*)(p3 + w0);
            float L0 = p0[wl], R0 = p0[wr];
            float L1 = p1[wl], R1 = p1[wr];
            float L2 = p2[wl], R2 = p2[wr];
            float L3 = p3[wl], R3 = p3[wr];
            col[0][0] = L0; col[0][1] = v0.x; col[0][2] = v0.y; col[0][3] = v0.z; col[0][4] = v0.w; col[0][5] = R0;
            col[1][0] = L1; col[1][1] = v1.x; col[1][2] = v1.y; col[1][3] = v1.z; col[1][4] = v1.w; col[1][5] = R1;
            col[2][0] = L2; col[2][1] = v2.x; col[2][2] = v2.y; col[2][3] = v2.z; col[2][4] = v2.w; col[2][5] = R2;
            col[3][0] = L3; col[3][1] = v3.x; col[3][2] = v3.y; col[3][3] = v3.z; col[3][4] = v3.w; col[3][5] = R3;
        }
        // horizontal diffs, shared between the two output rows
        float t[4][4];
#pragma unroll
        for (int r = 0; r < 4; ++r)
#pragma unroll
            for (int i = 0; i < 4; ++i)
                t[r][i] = col[r][i + 2] - col[r][i];
        // vertical diffs
        float u[2][6];
#pragma unroll
        for (int rr = 0; rr < 2; ++rr)
#pragma unroll
            for (int j = 0; j < 6; ++j)
                u[rr][j] = col[rr + 2][j] - col[rr][j];
#pragma unroll
        for (int rr = 0; rr < 2; ++rr) {
#pragma unroll
            for (int i = 0; i < 4; ++i) {
                float gx = 0.125f * (t[rr][i] + t[rr + 2][i]) + 0.25f * t[rr + 1][i];
                float gy = 0.125f * (u[rr][i] + u[rr][i + 2]) + 0.25f * u[rr][i + 1];
                float m = __builtin_amdgcn_sqrtf(gx * gx + gy * gy + 1e-9f);
                if (c == 0) {
                    bm[rr][i] = m; bgx[rr][i] = gx; bgy[rr][i] = gy;
                } else {
                    bool gt = m > bm[rr][i];   // strict > = first-occurrence argmax
                    bm[rr][i]  = gt ? m  : bm[rr][i];
                    bgx[rr][i] = gt ? gx : bgx[rr][i];
                    bgy[rr][i] = gt ? gy : bgy[rr][i];
                }
            }
        }
    }

    size_t npix = (size_t)B * (Hc * Wc);
#pragma unroll
    for (int rr = 0; rr < 2; ++rr) {
        float mo[4], ao[4];
#pragma unroll
        for (int i = 0; i < 4; ++i) {
            mo[i] = bm[rr][i];
            float yt = (bgy[rr][i] == 0.0f) ? 1e-9f : bgy[rr][i];
            float a = bgx[rr][i] * __builtin_amdgcn_rcpf(yt);  // clipped to ±10 anyway
            ao[i] = fminf(fmaxf(a, -10.0f), 10.0f);
        }
        // uniform output row base + lane offset -> saddr store
        size_t obase = ((size_t)b * Hc + (h0 + rr)) * Wc;
        float* po = out + obase;
        *(float4*)(po + w0)        = make_float4(mo[0], mo[1], mo[2], mo[3]);
        *(float4*)(po + npix + w0) = make_float4(ao[0], ao[1], ao[2], ao[3]);
    }
}

extern "C" void kernel_launch(void* const* d_in, const int* in_sizes, int n_in,
                              void* d_out, int out_size, void* d_ws, size_t ws_size,
                              hipStream_t stream) {
    const float* x = (const float*)d_in[0];
    float* out = (float*)d_out;
    int B = in_sizes[0] / (Cc * Hc * Wc);            // 16
    int total_threads = B * (Hc / 2) * (Wc / 4);     // 524288
    int blocks = total_threads / 256;                // 2048, exact
    sobel_mag_angle_kernel<<<blocks, 256, 0, stream>>>(x, out, B);
}

// Round 7
// 102.737 us; speedup vs baseline: 1.2459x; 1.2459x over previous
//
#include <hip/hip_runtime.h>

// x: (16, 3, 512, 512) fp32 -> magnitude (b,h,w) ++ angle (b,h,w), fp32.
// Sobel (kornia normalized, cross-correlation, 'edge' padding = clamp):
//   gx = 0.125*(r0[w+1]-r0[w-1]) + 0.25*(r1[w+1]-r1[w-1]) + 0.125*(r2[w+1]-r2[w-1])
//   gy = 0.125*(r2[w-1]-r0[w-1]) + 0.25*(r2[w]-r0[w]) + 0.125*(r2[w+1]-r0[w+1])
// Thread = 4 px x 1 output row, online argmax across channels.
// Working set ~45 VGPR -> fits the 64-VGPR quantum for 8 waves/SIMD
// (R6 lesson: 2-row version spilled at this bound; occupancy 66% gave 3.4 TB/s).
// Input (50 MB) fits L3, so losing vertical reuse costs ~0 HBM fetch.

constexpr int Hc = 512;
constexpr int Wc = 512;
constexpr int Cc = 3;

__global__ __launch_bounds__(256, 8) void sobel_mag_angle_kernel(
    const float* __restrict__ x, float* __restrict__ out, int B) {
    int tid = blockIdx.x * 256 + threadIdx.x;
    int l  = tid & 127;                 // 128 threads span one row (4 px each)
    int w0 = l << 2;

    // Wave-uniform components -> SGPR.
    int h = __builtin_amdgcn_readfirstlane((tid >> 7) & (Hc - 1));
    int b = __builtin_amdgcn_readfirstlane(tid >> 16);
    int rm = (h == 0) ? 0 : h - 1;             // clamped row above
    int rp = (h + 1 < Hc) ? h + 1 : Hc - 1;    // clamped row below

    // Lane-varying clamped halo columns ('edge' padding).
    int wl = (w0 == 0) ? 0 : w0 - 1;
    int wr = (w0 + 4 < Wc) ? w0 + 4 : Wc - 1;

    const float* xb = x + (size_t)b * (Cc * Hc * Wc);

    float bm[4], bgx[4], bgy[4];

#pragma unroll
    for (int c = 0; c < Cc; ++c) {
        const float* base = xb + c * (Hc * Wc);   // uniform
        const float* p0 = base + rm * Wc;         // uniform row bases (SGPR)
        const float* p1 = base + h * Wc;
        const float* p2 = base + rp * Wc;

        // cols 0..5 = image cols w0-1 .. w0+4 (clamped at edges)
        float col[3][6];
        {
            float4 v0 = *(const float4*)(p0 + w0);
            float4 v1 = *(const float4*)(p1 + w0);
            float4 v2 = *(const float4*)(p2 + w0);
            float L0 = p0[wl], R0 = p0[wr];
            float L1 = p1[wl], R1 = p1[wr];
            float L2 = p2[wl], R2 = p2[wr];
            col[0][0] = L0; col[0][1] = v0.x; col[0][2] = v0.y; col[0][3] = v0.z; col[0][4] = v0.w; col[0][5] = R0;
            col[1][0] = L1; col[1][1] = v1.x; col[1][2] = v1.y; col[1][3] = v1.z; col[1][4] = v1.w; col[1][5] = R1;
            col[2][0] = L2; col[2][1] = v2.x; col[2][2] = v2.y; col[2][3] = v2.z; col[2][4] = v2.w; col[2][5] = R2;
        }
#pragma unroll
        for (int i = 0; i < 4; ++i) {
            float t0 = col[0][i + 2] - col[0][i];
            float t1 = col[1][i + 2] - col[1][i];
            float t2 = col[2][i + 2] - col[2][i];
            float gx = 0.125f * (t0 + t2) + 0.25f * t1;
            float u0 = col[2][i]     - col[0][i];
            float u1 = col[2][i + 1] - col[0][i + 1];
            float u2 = col[2][i + 2] - col[0][i + 2];
            float gy = 0.125f * (u0 + u2) + 0.25f * u1;
            float m = __builtin_amdgcn_sqrtf(gx * gx + gy * gy + 1e-9f);
            if (c == 0) {
                bm[i] = m; bgx[i] = gx; bgy[i] = gy;
            } else {
                bool gt = m > bm[i];   // strict > = first-occurrence argmax
                bm[i]  = gt ? m  : bm[i];
                bgx[i] = gt ? gx : bgx[i];
                bgy[i] = gt ? gy : bgy[i];
            }
        }
    }

    float mo[4], ao[4];
#pragma unroll
    for (int i = 0; i < 4; ++i) {
        mo[i] = bm[i];
        float yt = (bgy[i] == 0.0f) ? 1e-9f : bgy[i];
        float a = bgx[i] * __builtin_amdgcn_rcpf(yt);  // clipped to ±10 anyway
        ao[i] = fminf(fmaxf(a, -10.0f), 10.0f);
    }

    size_t npix = (size_t)B * (Hc * Wc);
    size_t obase = ((size_t)b * Hc + h) * Wc;
    float* po = out + obase;                 // uniform base + lane offset
    *(float4*)(po + w0)        = make_float4(mo[0], mo[1], mo[2], mo[3]);
    *(float4*)(po + npix + w0) = make_float4(ao[0], ao[1], ao[2], ao[3]);
}

extern "C" void kernel_launch(void* const* d_in, const int* in_sizes, int n_in,
                              void* d_out, int out_size, void* d_ws, size_t ws_size,
                              hipStream_t stream) {
    const float* x = (const float*)d_in[0];
    float* out = (float*)d_out;
    int B = in_sizes[0] / (Cc * Hc * Wc);        // 16
    int total_threads = B * Hc * (Wc / 4);       // 1048576
    int blocks = total_threads / 256;            // 4096, exact
    sobel_mag_angle_kernel<<<blocks, 256, 0, stream>>>(x, out, B);
}

// Round 8
// 96.313 us; speedup vs baseline: 1.3290x; 1.0667x over previous
//
#include <hip/hip_runtime.h>
#include <stdint.h>

// x: (16, 3, 512, 512) fp32 -> magnitude (b,h,w) ++ angle (b,h,w), fp32.
// Sobel (kornia normalized, cross-correlation, 'edge' padding = clamp):
//   gx = 0.125*(r0[w+1]-r0[w-1]) + 0.25*(r1[w+1]-r1[w-1]) + 0.125*(r2[w+1]-r2[w-1])
//   gy = 0.125*(r2[w-1]-r0[w-1]) + 0.25*(r2[w]-r0[w]) + 0.125*(r2[w+1]-r0[w+1])
//
// R8 structure: global_load_lds staging (fire-and-forget, no VGPR dests ->
// ~72 cache lines in flight per wave vs ~5 for register loads). Block stages
// 3ch x 6rows x 512 = 36KB, one vmcnt(0)+barrier, each wave computes one
// 512-px output row from LDS. 4 blocks/CU (LDS-bound).

constexpr int Hc = 512;
constexpr int Wc = 512;
constexpr int Cc = 3;
constexpr int RT = 4;            // output rows per block (one per wave)
constexpr int TR = RT + 2;       // staged rows per channel (with vertical halo)

__global__ __launch_bounds__(256, 4) void sobel_mag_angle_kernel(
    const float* __restrict__ x, float* __restrict__ out, int B) {
    __shared__ float lds[Cc * TR * Wc];          // 9216 floats = 36 KB

    int bid = blockIdx.x;
    int b  = bid >> 7;                           // 128 h-tiles per batch image
    int h0 = (bid & 127) * RT;

    int t = threadIdx.x;
    int wave = t >> 6;                           // 0..3 (wave-uniform)
    int lane = t & 63;

    // ---- Stage: 36 global_load_lds wave-instrs total, 9 per wave ----
    // stage s: ch = s/12, tile row rr = (s%12)/2, half = s&1 (256 floats each)
    const float* xb = x + (size_t)b * (Cc * Hc * Wc);
#pragma unroll
    for (int s2 = 0; s2 < 9; ++s2) {
        int s = wave * 9 + s2;
        int ch = s / 12;
        int rr = (s % 12) >> 1;
        int half = s & 1;
        int srow = h0 + rr - 1;                               // vertical clamp
        srow = srow < 0 ? 0 : (srow > Hc - 1 ? Hc - 1 : srow);
        const float* gp = xb + ((size_t)ch * Hc + srow) * Wc + half * 256 + lane * 4;
        float* lp = &lds[(ch * TR + rr) * Wc + half * 256];   // wave-uniform base
        __builtin_amdgcn_global_load_lds(
            (const __attribute__((address_space(1))) void*)gp,
            (__attribute__((address_space(3))) void*)lp, 16, 0, 0);
    }
    asm volatile("s_waitcnt vmcnt(0)" ::: "memory");
    __syncthreads();

    // ---- Compute: wave r handles output row h0+r, lane covers 8 px ----
    int r = wave;
    int w0 = lane << 3;
    int wl = (w0 == 0) ? 0 : w0 - 1;             // horizontal clamp (lane 0)
    int wr = (w0 + 8 < Wc) ? w0 + 8 : Wc - 1;    // horizontal clamp (lane 63)

    float bm[8], bgx[8], bgy[8];
#pragma unroll
    for (int c = 0; c < Cc; ++c) {
        float row[3][10];                         // cols w0-1 .. w0+8
#pragma unroll
        for (int k = 0; k < 3; ++k) {
            const float* lrow = &lds[(c * TR + (r + k)) * Wc];
            float4 A  = *(const float4*)(lrow + w0);
            float4 Bv = *(const float4*)(lrow + w0 + 4);
            row[k][0] = lrow[wl];
            row[k][1] = A.x;  row[k][2] = A.y;  row[k][3] = A.z;  row[k][4] = A.w;
            row[k][5] = Bv.x; row[k][6] = Bv.y; row[k][7] = Bv.z; row[k][8] = Bv.w;
            row[k][9] = lrow[wr];
        }
#pragma unroll
        for (int i = 0; i < 8; ++i) {
            float t0 = row[0][i + 2] - row[0][i];
            float t1 = row[1][i + 2] - row[1][i];
            float t2 = row[2][i + 2] - row[2][i];
            float gx = 0.125f * (t0 + t2) + 0.25f * t1;
            float u0 = row[2][i]     - row[0][i];
            float u1 = row[2][i + 1] - row[0][i + 1];
            float u2 = row[2][i + 2] - row[0][i + 2];
            float gy = 0.125f * (u0 + u2) + 0.25f * u1;
            float m = __builtin_amdgcn_sqrtf(gx * gx + gy * gy + 1e-9f);
            if (c == 0) {
                bm[i] = m; bgx[i] = gx; bgy[i] = gy;
            } else {
                bool gt = m > bm[i];   // strict > = first-occurrence argmax
                bm[i]  = gt ? m  : bm[i];
                bgx[i] = gt ? gx : bgx[i];
                bgy[i] = gt ? gy : bgy[i];
            }
        }
    }

    float mo[8], ao[8];
#pragma unroll
    for (int i = 0; i < 8; ++i) {
        mo[i] = bm[i];
        float yt = (bgy[i] == 0.0f) ? 1e-9f : bgy[i];
        float a = bgx[i] * __builtin_amdgcn_rcpf(yt);  // clipped to ±10 anyway
        ao[i] = fminf(fmaxf(a, -10.0f), 10.0f);
    }

    size_t npix = (size_t)B * (Hc * Wc);
    size_t obase = ((size_t)b * Hc + (h0 + r)) * Wc;
    float* po = out + obase;
    *(float4*)(po + w0)            = make_float4(mo[0], mo[1], mo[2], mo[3]);
    *(float4*)(po + w0 + 4)        = make_float4(mo[4], mo[5], mo[6], mo[7]);
    *(float4*)(po + npix + w0)     = make_float4(ao[0], ao[1], ao[2], ao[3]);
    *(float4*)(po + npix + w0 + 4) = make_float4(ao[4], ao[5], ao[6], ao[7]);
}

extern "C" void kernel_launch(void* const* d_in, const int* in_sizes, int n_in,
                              void* d_out, int out_size, void* d_ws, size_t ws_size,
                              hipStream_t stream) {
    const float* x = (const float*)d_in[0];
    float* out = (float*)d_out;
    int B = in_sizes[0] / (Cc * Hc * Wc);        // 16
    int blocks = B * (Hc / RT);                  // 2048
    sobel_mag_angle_kernel<<<blocks, 256, 0, stream>>>(x, out, B);
}